// Round 8
// baseline (267.058 us; speedup 1.0000x reference)
//
#include <hip/hip_runtime.h>
#include <cmath>

constexpr int NN   = 100000;
constexpr int NE   = 3200000;
constexpr int DIN  = 128;
constexpr int DH   = 32;
constexpr int DOUT = 20;

constexpr int NB    = 392;                 // coarse buckets: dst>>8 -> 0..390 (+1 pad)
constexpr int NBUSE = (NN + 255) / 256;    // 391 buckets actually used
constexpr int NBLK  = 256;                 // phase A/C blocks
constexpr int SLICE = NE / NBLK;           // 12500 edges per block (exact)

constexpr int NPB = 64;                    // nodes per lin1 block
constexpr int XS  = 132;                   // padded LDS row stride (float4-aligned)

__device__ inline unsigned short f2bf(float f) {           // RNE float->bf16
    unsigned u = __builtin_bit_cast(unsigned, f);
    unsigned r = 0x7FFFu + ((u >> 16) & 1u);
    return (unsigned short)((u + r) >> 16);
}
__device__ inline float bflo(unsigned u) {                 // low ushort -> float
    return __builtin_bit_cast(float, u << 16);
}
__device__ inline float bfhi(unsigned u) {                 // high ushort -> float
    return __builtin_bit_cast(float, u & 0xFFFF0000u);
}

// ---------------- layer-1 projections: xl(bf16) = x@W1l, xr(f32) = x@W1r ----------------
// launch_bounds(256,4): 4 waves/EU min -> VGPR cap 128, gives the scheduler
// room to keep a full 16-float4 W stage in flight under the FMAs.
__global__ __launch_bounds__(256, 4) void lin1_kernel(
    const float* __restrict__ x, const float* __restrict__ Wl,
    const float* __restrict__ Wr, unsigned short* __restrict__ xlbf,
    float* __restrict__ xr)
{
    __shared__ float xs[NPB * XS];         // 33792 B -> 4 blocks/CU
    int t = threadIdx.x;
    int nodeBase = blockIdx.x * NPB;

    const float4* x4 = reinterpret_cast<const float4*>(x) + (size_t)nodeBase * (DIN / 4);
    for (int i = t; i < NPB * (DIN / 4); i += 256) {
        int n = i >> 5, c = i & 31;
        float4 v = make_float4(0.f, 0.f, 0.f, 0.f);
        if (nodeBase + n < NN) v = x4[i];
        *reinterpret_cast<float4*>(&xs[n * XS + c * 4]) = v;   // b128, aligned
    }
    __syncthreads();

    int wv   = __builtin_amdgcn_readfirstlane(t >> 6);   // 0..3
    int lane = t & 63;
    int node = nodeBase + lane;
    const float* W = (wv & 2) ? Wr : Wl;
    int jbase = (wv & 1) * 16;
    const float* Wj = W + jbase;

    float acc[16];
#pragma unroll
    for (int j = 0; j < 16; ++j) acc[j] = 0.f;

    const float* xrow = &xs[lane * XS];
#pragma unroll
    for (int k0 = 0; k0 < DIN; k0 += 4) {
        float4 xv = *reinterpret_cast<const float4*>(xrow + k0);   // 1 ds_read_b128 / 4 k
        float4 w[16];                                              // stage: 16 loads first
#pragma unroll
        for (int kk = 0; kk < 4; ++kk) {
            const float4* w4 = reinterpret_cast<const float4*>(Wj + (k0 + kk) * DH);
            w[kk*4+0] = w4[0]; w[kk*4+1] = w4[1];
            w[kk*4+2] = w4[2]; w[kk*4+3] = w4[3];
        }
        float xk[4] = {xv.x, xv.y, xv.z, xv.w};
#pragma unroll
        for (int kk = 0; kk < 4; ++kk) {
#pragma unroll
            for (int q = 0; q < 4; ++q) {
                float4 ww = w[kk*4+q];
                acc[q*4+0] = fmaf(xk[kk], ww.x, acc[q*4+0]);
                acc[q*4+1] = fmaf(xk[kk], ww.y, acc[q*4+1]);
                acc[q*4+2] = fmaf(xk[kk], ww.z, acc[q*4+2]);
                acc[q*4+3] = fmaf(xk[kk], ww.w, acc[q*4+3]);
            }
        }
    }
    if (node < NN) {
        if (wv & 2) {
            float4* o4 = reinterpret_cast<float4*>(xr + (size_t)node * DH + jbase);
#pragma unroll
            for (int q = 0; q < 4; ++q)
                o4[q] = make_float4(acc[q*4+0], acc[q*4+1], acc[q*4+2], acc[q*4+3]);
        } else {
            unsigned pk[8];
#pragma unroll
            for (int q = 0; q < 8; ++q)
                pk[q] = (unsigned)f2bf(acc[q*2]) | ((unsigned)f2bf(acc[q*2+1]) << 16);
            uint4* o4 = reinterpret_cast<uint4*>(xlbf + (size_t)node * DH + jbase);
            o4[0] = make_uint4(pk[0], pk[1], pk[2], pk[3]);
            o4[1] = make_uint4(pk[4], pk[5], pk[6], pk[7]);
        }
    }
}

// ---------------- phase A: per-block coarse-bucket histogram ----------------
__global__ __launch_bounds__(256) void countA_kernel(
    const int* __restrict__ ei, int* __restrict__ counts)
{
    __shared__ int h[NB];
    int blk = blockIdx.x, t = threadIdx.x;
    for (int i = t; i < NB; i += 256) h[i] = 0;
    __syncthreads();
    int base = blk * SLICE;
    for (int i = base + t; i < base + SLICE; i += 256) {
        int dst = ei[NE + i];
        atomicAdd(&h[dst >> 8], 1);
    }
    __syncthreads();
    for (int i = t; i < NB; i += 256) counts[blk * NB + i] = h[i];
}

// ------- phase B1: per-bucket exclusive scan over 256 block counts -------
__global__ __launch_bounds__(256) void scanB1_kernel(
    const int* __restrict__ counts, int* __restrict__ offs, int* __restrict__ totals)
{
    __shared__ int sdata[256];
    int b = blockIdx.x, t = threadIdx.x;
    int v = counts[t * NB + b];
    sdata[t] = v;
    __syncthreads();
    for (int off = 1; off < 256; off <<= 1) {
        int tmp = (t >= off) ? sdata[t - off] : 0;
        __syncthreads();
        sdata[t] += tmp;
        __syncthreads();
    }
    offs[b * 256 + t] = sdata[t] - v;
    if (t == 255) totals[b] = sdata[255];
}

// ------- phase B2: exclusive scan of bucket totals (tiny) -------
__global__ void scanB2_kernel(const int* __restrict__ totals, int* __restrict__ bases)
{
    if (threadIdx.x == 0 && blockIdx.x == 0) {
        int acc = 0;
        for (int i = 0; i < NB; ++i) { bases[i] = acc; acc += totals[i]; }
        bases[NB] = acc;
    }
}

// ------- phase C: rank-based scatter into per-(block,bucket) private regions -------
__global__ __launch_bounds__(256) void scatterC_kernel(
    const int* __restrict__ ei, const int* __restrict__ offs,
    const int* __restrict__ bases, unsigned* __restrict__ csrtmp)
{
    __shared__ int cnt[NB];
    __shared__ int wbase[NB];
    int blk = blockIdx.x, t = threadIdx.x;
    for (int i = t; i < NB; i += 256) {
        cnt[i] = 0;
        wbase[i] = bases[i] + offs[i * 256 + blk];
    }
    __syncthreads();
    int base = blk * SLICE;
    for (int i = base + t; i < base + SLICE; i += 256) {
        int dst = ei[NE + i];
        int src = ei[i];
        int b = dst >> 8;
        int r = atomicAdd(&cnt[b], 1);                       // LDS atomic
        csrtmp[wbase[b] + r] = ((unsigned)(dst & 255) << 17) | (unsigned)src;
    }
}

// ------- phase D: regroup within bucket -> final CSR + start + deg -------
__global__ __launch_bounds__(256) void regroupD_kernel(
    const unsigned* __restrict__ csrtmp, const int* __restrict__ bases,
    int* __restrict__ csrsrc, int* __restrict__ deg, int* __restrict__ start)
{
    __shared__ int h[256];
    __shared__ int sdata[256];
    int b = blockIdx.x, t = threadIdx.x;
    int lo = bases[b], hi = bases[b + 1];
    h[t] = 0;
    __syncthreads();
    for (int i = lo + t; i < hi; i += 256)
        atomicAdd(&h[csrtmp[i] >> 17], 1);
    __syncthreads();
    int v = h[t];
    sdata[t] = v;
    __syncthreads();
    for (int off = 1; off < 256; off <<= 1) {
        int tmp = (t >= off) ? sdata[t - off] : 0;
        __syncthreads();
        sdata[t] += tmp;
        __syncthreads();
    }
    int ex = sdata[t] - v;
    int node = b * 256 + t;
    if (node < NN) { start[node] = lo + ex; deg[node] = v; }
    h[t] = ex;
    __syncthreads();
    for (int i = lo + t; i < hi; i += 256) {
        unsigned u = csrtmp[i];
        int r = atomicAdd(&h[u >> 17], 1);   // LDS atomic
        csrsrc[lo + r] = (int)(u & 0x1FFFFu);
    }
}

// ------- gather (bf16 feat rows, 64 B/row): agg[g] = sum over neighbors -------
__global__ __launch_bounds__(256) void gather_kernel(
    const int* __restrict__ start, const int* __restrict__ deg,
    const int* __restrict__ csrsrc, const unsigned short* __restrict__ feat,
    float* __restrict__ agg)
{
    int tid = blockIdx.x * 256 + threadIdx.x;
    int g = tid >> 3;            // node
    int c = tid & 7;             // uint2 chunk (4 bf16) of the 32-dim row
    if (g >= NN) return;
    int s = start[g];
    int e = s + deg[g];
    const uint2* f2 = reinterpret_cast<const uint2*>(feat);
    float4 a0 = make_float4(0.f, 0.f, 0.f, 0.f);
    float4 a1 = make_float4(0.f, 0.f, 0.f, 0.f);
    int i = s;
    for (; i + 2 <= e; i += 2) {
        int s0 = csrsrc[i];
        int s1 = csrsrc[i + 1];
        uint2 v0 = f2[(size_t)s0 * 8 + c];
        uint2 v1 = f2[(size_t)s1 * 8 + c];
        a0.x += bflo(v0.x); a0.y += bfhi(v0.x); a0.z += bflo(v0.y); a0.w += bfhi(v0.y);
        a1.x += bflo(v1.x); a1.y += bfhi(v1.x); a1.z += bflo(v1.y); a1.w += bfhi(v1.y);
    }
    if (i < e) {
        int s0 = csrsrc[i];
        uint2 v0 = f2[(size_t)s0 * 8 + c];
        a0.x += bflo(v0.x); a0.y += bfhi(v0.x); a0.z += bflo(v0.y); a0.w += bfhi(v0.y);
    }
    a0.x += a1.x; a0.y += a1.y; a0.z += a1.z; a0.w += a1.w;
    reinterpret_cast<float4*>(agg)[(size_t)g * 8 + c] = a0;
}

// ---- post layer1: o = agg/deg + b1 + xr; h1 = tanh(l2norm(o));
//      hl(bf16) = h1@W2l, hr(f32) = h1@W2r ----
__global__ __launch_bounds__(256) void post1_kernel(
    const float* __restrict__ agg, const int* __restrict__ deg,
    const float* __restrict__ xr, const float* __restrict__ b1,
    const float* __restrict__ W2l, const float* __restrict__ W2r,
    unsigned short* __restrict__ hlbf, float* __restrict__ hr)
{
    int node = blockIdx.x * 256 + threadIdx.x;
    if (node >= NN) return;
    float inv = 1.0f / fmaxf((float)deg[node], 1.0f);
    float o[DH];
    const float4* ag4 = reinterpret_cast<const float4*>(agg + (size_t)node * DH);
    const float4* xr4 = reinterpret_cast<const float4*>(xr  + (size_t)node * DH);
#pragma unroll
    for (int q = 0; q < DH / 4; ++q) {
        float4 a = ag4[q]; float4 r = xr4[q];
        o[q*4+0] = fmaf(a.x, inv, b1[q*4+0] + r.x);
        o[q*4+1] = fmaf(a.y, inv, b1[q*4+1] + r.y);
        o[q*4+2] = fmaf(a.z, inv, b1[q*4+2] + r.z);
        o[q*4+3] = fmaf(a.w, inv, b1[q*4+3] + r.w);
    }
    float ss = 0.f;
#pragma unroll
    for (int j = 0; j < DH; ++j) ss += o[j] * o[j];
    float rn = 1.0f / fmaxf(sqrtf(ss), 1e-12f);
    float h[DH];
#pragma unroll
    for (int j = 0; j < DH; ++j) h[j] = tanhf(o[j] * rn);

    float al[DH], ar[DH];
#pragma unroll
    for (int j = 0; j < DH; ++j) { al[j] = 0.f; ar[j] = 0.f; }
    for (int k = 0; k < DH; ++k) {
        float hk = h[k];
        const float* wl = W2l + k * DH;
        const float* wr = W2r + k * DH;
#pragma unroll
        for (int j = 0; j < DH; ++j) {
            al[j] = fmaf(hk, wl[j], al[j]);
            ar[j] = fmaf(hk, wr[j], ar[j]);
        }
    }
    unsigned pk[16];
#pragma unroll
    for (int q = 0; q < 16; ++q)
        pk[q] = (unsigned)f2bf(al[q*2]) | ((unsigned)f2bf(al[q*2+1]) << 16);
    uint4* hl4 = reinterpret_cast<uint4*>(hlbf + (size_t)node * DH);
    hl4[0] = make_uint4(pk[0],  pk[1],  pk[2],  pk[3]);
    hl4[1] = make_uint4(pk[4],  pk[5],  pk[6],  pk[7]);
    hl4[2] = make_uint4(pk[8],  pk[9],  pk[10], pk[11]);
    hl4[3] = make_uint4(pk[12], pk[13], pk[14], pk[15]);
    float4* hr4 = reinterpret_cast<float4*>(hr + (size_t)node * DH);
#pragma unroll
    for (int q = 0; q < DH / 4; ++q)
        hr4[q] = make_float4(ar[q*4+0], ar[q*4+1], ar[q*4+2], ar[q*4+3]);
}

// ---- post layer2 + classifier ----
__global__ __launch_bounds__(256) void post2_kernel(
    const float* __restrict__ agg, const int* __restrict__ deg,
    const float* __restrict__ hr, const float* __restrict__ b2,
    const float* __restrict__ Wc, const float* __restrict__ bc,
    float* __restrict__ h2out, float* __restrict__ outp)
{
    int node = blockIdx.x * 256 + threadIdx.x;
    if (node >= NN) return;
    float inv = 1.0f / fmaxf((float)deg[node], 1.0f);
    float o[DH];
    const float4* ag4 = reinterpret_cast<const float4*>(agg + (size_t)node * DH);
    const float4* hr4 = reinterpret_cast<const float4*>(hr  + (size_t)node * DH);
#pragma unroll
    for (int q = 0; q < DH / 4; ++q) {
        float4 a = ag4[q]; float4 r = hr4[q];
        o[q*4+0] = fmaf(a.x, inv, b2[q*4+0] + r.x);
        o[q*4+1] = fmaf(a.y, inv, b2[q*4+1] + r.y);
        o[q*4+2] = fmaf(a.z, inv, b2[q*4+2] + r.z);
        o[q*4+3] = fmaf(a.w, inv, b2[q*4+3] + r.w);
    }
    float ss = 0.f;
#pragma unroll
    for (int j = 0; j < DH; ++j) ss += o[j] * o[j];
    float rn = 1.0f / fmaxf(sqrtf(ss), 1e-12f);
    float h[DH];
#pragma unroll
    for (int j = 0; j < DH; ++j) h[j] = tanhf(o[j] * rn);

    float4* h2o = reinterpret_cast<float4*>(h2out + (size_t)node * DH);
#pragma unroll
    for (int q = 0; q < DH / 4; ++q)
        h2o[q] = make_float4(h[q*4+0], h[q*4+1], h[q*4+2], h[q*4+3]);

    float z[DOUT];
#pragma unroll
    for (int t = 0; t < DOUT; ++t) z[t] = bc[t];
    for (int k = 0; k < DH; ++k) {
        float hk = h[k];
        const float* wc = Wc + k * DOUT;
#pragma unroll
        for (int t = 0; t < DOUT; ++t) z[t] = fmaf(hk, wc[t], z[t]);
    }
    float m = -INFINITY;
#pragma unroll
    for (int t = 0; t < DOUT; ++t) m = fmaxf(m, z[t]);
    float s = 0.f;
#pragma unroll
    for (int t = 0; t < DOUT; ++t) s += expf(z[t] - m);
    float lse = m + logf(s);
    float* orow = outp + (size_t)node * DOUT;
#pragma unroll
    for (int t = 0; t < DOUT; ++t) orow[t] = z[t] - lse;
}

extern "C" void kernel_launch(void* const* d_in, const int* in_sizes, int n_in,
                              void* d_out, int out_size, void* d_ws, size_t ws_size,
                              hipStream_t stream) {
    const float* x   = (const float*)d_in[0];
    const int*   ei  = (const int*)d_in[1];
    const float* W1l = (const float*)d_in[2];
    const float* b1  = (const float*)d_in[3];
    const float* W1r = (const float*)d_in[4];
    const float* W2l = (const float*)d_in[5];
    const float* b2  = (const float*)d_in[6];
    const float* W2r = (const float*)d_in[7];
    const float* Wc  = (const float*)d_in[8];
    const float* bc  = (const float*)d_in[9];

    float* outp = (float*)d_out;                          // [NN, 20]
    float* hout = outp + (size_t)NN * DOUT;               // [NN, 32]

    // workspace layout
    unsigned short* xlbf = (unsigned short*)d_ws;         // NN*DH bf16 (6.4 MB)
    float* xr      = (float*)(xlbf + (size_t)NN * DH);    // NN*DH f32 (also hr)
    float* agg     = xr + (size_t)NN * DH;                // NN*DH f32 (aliases csrtmp)
    unsigned* csrtmp = (unsigned*)agg;                    // NE u32
    int* csrsrc    = (int*)(agg + (size_t)NN * DH);       // NE
    int* deg       = csrsrc + NE;                         // NN
    int* start     = deg + NN;                            // NN
    int* counts    = start + NN;                          // NBLK*NB
    int* offs      = counts + NBLK * NB;                  // NB*NBLK
    int* totals    = offs + NB * NBLK;                    // NB
    int* bases     = totals + NB;                         // NB+1

    const int nodeBlocks  = (NN + 255) / 256;
    const int lin1Blocks  = (NN + NPB - 1) / NPB;
    const int groupBlocks = (NN * 8 + 255) / 256;

    lin1_kernel<<<lin1Blocks, 256, 0, stream>>>(x, W1l, W1r, xlbf, xr);

    countA_kernel<<<NBLK, 256, 0, stream>>>(ei, counts);
    scanB1_kernel<<<NB, 256, 0, stream>>>(counts, offs, totals);
    scanB2_kernel<<<1, 64, 0, stream>>>(totals, bases);
    scatterC_kernel<<<NBLK, 256, 0, stream>>>(ei, offs, bases, csrtmp);
    regroupD_kernel<<<NBUSE, 256, 0, stream>>>(csrtmp, bases, csrsrc, deg, start);

    gather_kernel<<<groupBlocks, 256, 0, stream>>>(start, deg, csrsrc, xlbf, agg);
    post1_kernel<<<nodeBlocks, 256, 0, stream>>>(agg, deg, xr, b1, W2l, W2r, xlbf, xr);

    gather_kernel<<<groupBlocks, 256, 0, stream>>>(start, deg, csrsrc, xlbf, agg);
    post2_kernel<<<nodeBlocks, 256, 0, stream>>>(agg, deg, xr, b2, Wc, bc, hout, outp);
}

// Round 9
// 232.206 us; speedup vs baseline: 1.1501x; 1.1501x over previous
//
#include <hip/hip_runtime.h>
#include <cmath>

constexpr int NN   = 100000;
constexpr int NE   = 3200000;
constexpr int DIN  = 128;
constexpr int DH   = 32;
constexpr int DOUT = 20;

constexpr int NB    = 392;                 // coarse buckets: dst>>8 -> 0..390 (+1 pad)
constexpr int NBUSE = (NN + 255) / 256;    // 391 buckets actually used
constexpr int NBLK  = 256;                 // phase A/C blocks
constexpr int SLICE = NE / NBLK;           // 12500 edges per block (exact)

constexpr int NPB = 64;                    // nodes per lin1 block
constexpr int XSB = 136;                   // bf16 LDS row stride (16B-aligned, 2-way banks)

typedef __attribute__((ext_vector_type(8))) short short8v;   // 8 bf16 (4 VGPRs)
typedef __attribute__((ext_vector_type(4))) float f32x4;     // MFMA accumulator

__device__ inline unsigned short f2bf(float f) {           // RNE float->bf16
    unsigned u = __builtin_bit_cast(unsigned, f);
    unsigned r = 0x7FFFu + ((u >> 16) & 1u);
    return (unsigned short)((u + r) >> 16);
}
__device__ inline float bflo(unsigned u) {                 // low ushort -> float
    return __builtin_bit_cast(float, u << 16);
}
__device__ inline float bfhi(unsigned u) {                 // high ushort -> float
    return __builtin_bit_cast(float, u & 0xFFFF0000u);
}

// ---------------- layer-1 projections via MFMA: xl(bf16)=x@W1l, xr(f32)=x@W1r ----------
// 4 waves/block, 64 nodes/block. Wave wv owns a 16-col slice: {Wl,Wr} x {j 0-15,16-31}.
// B-frags (W slice) live in VGPRs for the whole block; A-frags stream from bf16 LDS.
__global__ __launch_bounds__(256, 4) void lin1_kernel(
    const float* __restrict__ x, const float* __restrict__ Wl,
    const float* __restrict__ Wr, unsigned short* __restrict__ xlbf,
    float* __restrict__ xr)
{
    __shared__ unsigned short xs[NPB * XSB];   // 17408 B
    int t = threadIdx.x;
    int nodeBase = blockIdx.x * NPB;

    // stage x rows -> bf16 LDS (coalesced float4 reads, uint2 LDS writes)
    const float4* x4 = reinterpret_cast<const float4*>(x) + (size_t)nodeBase * (DIN / 4);
    for (int i = t; i < NPB * (DIN / 4); i += 256) {
        int n = i >> 5, c = i & 31;
        float4 v = make_float4(0.f, 0.f, 0.f, 0.f);
        if (nodeBase + n < NN) v = x4[i];
        unsigned lo = (unsigned)f2bf(v.x) | ((unsigned)f2bf(v.y) << 16);
        unsigned hi = (unsigned)f2bf(v.z) | ((unsigned)f2bf(v.w) << 16);
        *reinterpret_cast<uint2*>(&xs[n * XSB + c * 4]) = make_uint2(lo, hi);
    }
    __syncthreads();

    int wv   = t >> 6;                 // 0..3
    int lane = t & 63;
    const float* W = (wv & 2) ? Wr : Wl;
    int jbase = (wv & 1) * 16;
    int ncol  = jbase + (lane & 15);   // B: col = lane&15
    int krow  = (lane >> 4) * 8;       // B/A: k-chunk = (lane>>4)*8

    // B fragments: B[k][n], lane holds k = ks*32 + krow + e, col = ncol
    short8v bfrag[4];
#pragma unroll
    for (int ks = 0; ks < 4; ++ks) {
        const float* wp = W + (ks * 32 + krow) * DH + ncol;
        short8v f;
#pragma unroll
        for (int e = 0; e < 8; ++e) f[e] = (short)f2bf(wp[e * DH]);
        bfrag[ks] = f;
    }

    f32x4 acc[4];
#pragma unroll
    for (int m = 0; m < 4; ++m) acc[m] = f32x4{0.f, 0.f, 0.f, 0.f};

    // A: row = m*16 + (lane&15), k = ks*32 + krow + e  -> one ds_read_b128 per frag
#pragma unroll
    for (int m = 0; m < 4; ++m) {
        int row = m * 16 + (lane & 15);
#pragma unroll
        for (int ks = 0; ks < 4; ++ks) {
            short8v a = *reinterpret_cast<const short8v*>(&xs[row * XSB + ks * 32 + krow]);
            acc[m] = __builtin_amdgcn_mfma_f32_16x16x32_bf16(a, bfrag[ks], acc[m], 0, 0, 0);
        }
    }

    // D: col = lane&15, row = (lane>>4)*4 + r
#pragma unroll
    for (int m = 0; m < 4; ++m) {
        int rbase = m * 16 + (lane >> 4) * 4;
#pragma unroll
        for (int r = 0; r < 4; ++r) {
            int node = nodeBase + rbase + r;
            if (node < NN) {
                float v = acc[m][r];
                if (wv & 2) xr[(size_t)node * DH + ncol] = v;
                else        xlbf[(size_t)node * DH + ncol] = f2bf(v);
            }
        }
    }
}

// ---------------- phase A: per-block coarse-bucket histogram ----------------
__global__ __launch_bounds__(256) void countA_kernel(
    const int* __restrict__ ei, int* __restrict__ counts)
{
    __shared__ int h[NB];
    int blk = blockIdx.x, t = threadIdx.x;
    for (int i = t; i < NB; i += 256) h[i] = 0;
    __syncthreads();
    int base = blk * SLICE;
    for (int i = base + t; i < base + SLICE; i += 256) {
        int dst = ei[NE + i];
        atomicAdd(&h[dst >> 8], 1);
    }
    __syncthreads();
    for (int i = t; i < NB; i += 256) counts[blk * NB + i] = h[i];
}

// ------- phase B1: per-bucket exclusive scan over 256 block counts -------
__global__ __launch_bounds__(256) void scanB1_kernel(
    const int* __restrict__ counts, int* __restrict__ offs, int* __restrict__ totals)
{
    __shared__ int sdata[256];
    int b = blockIdx.x, t = threadIdx.x;
    int v = counts[t * NB + b];
    sdata[t] = v;
    __syncthreads();
    for (int off = 1; off < 256; off <<= 1) {
        int tmp = (t >= off) ? sdata[t - off] : 0;
        __syncthreads();
        sdata[t] += tmp;
        __syncthreads();
    }
    offs[b * 256 + t] = sdata[t] - v;
    if (t == 255) totals[b] = sdata[255];
}

// ------- phase B2: exclusive scan of bucket totals (tiny) -------
__global__ void scanB2_kernel(const int* __restrict__ totals, int* __restrict__ bases)
{
    if (threadIdx.x == 0 && blockIdx.x == 0) {
        int acc = 0;
        for (int i = 0; i < NB; ++i) { bases[i] = acc; acc += totals[i]; }
        bases[NB] = acc;
    }
}

// ------- phase C: rank-based scatter into per-(block,bucket) private regions -------
__global__ __launch_bounds__(256) void scatterC_kernel(
    const int* __restrict__ ei, const int* __restrict__ offs,
    const int* __restrict__ bases, unsigned* __restrict__ csrtmp)
{
    __shared__ int cnt[NB];
    __shared__ int wbase[NB];
    int blk = blockIdx.x, t = threadIdx.x;
    for (int i = t; i < NB; i += 256) {
        cnt[i] = 0;
        wbase[i] = bases[i] + offs[i * 256 + blk];
    }
    __syncthreads();
    int base = blk * SLICE;
    for (int i = base + t; i < base + SLICE; i += 256) {
        int dst = ei[NE + i];
        int src = ei[i];
        int b = dst >> 8;
        int r = atomicAdd(&cnt[b], 1);                       // LDS atomic
        csrtmp[wbase[b] + r] = ((unsigned)(dst & 255) << 17) | (unsigned)src;
    }
}

// ------- phase D: regroup within bucket -> final CSR + start + deg -------
__global__ __launch_bounds__(256) void regroupD_kernel(
    const unsigned* __restrict__ csrtmp, const int* __restrict__ bases,
    int* __restrict__ csrsrc, int* __restrict__ deg, int* __restrict__ start)
{
    __shared__ int h[256];
    __shared__ int sdata[256];
    int b = blockIdx.x, t = threadIdx.x;
    int lo = bases[b], hi = bases[b + 1];
    h[t] = 0;
    __syncthreads();
    for (int i = lo + t; i < hi; i += 256)
        atomicAdd(&h[csrtmp[i] >> 17], 1);
    __syncthreads();
    int v = h[t];
    sdata[t] = v;
    __syncthreads();
    for (int off = 1; off < 256; off <<= 1) {
        int tmp = (t >= off) ? sdata[t - off] : 0;
        __syncthreads();
        sdata[t] += tmp;
        __syncthreads();
    }
    int ex = sdata[t] - v;
    int node = b * 256 + t;
    if (node < NN) { start[node] = lo + ex; deg[node] = v; }
    h[t] = ex;
    __syncthreads();
    for (int i = lo + t; i < hi; i += 256) {
        unsigned u = csrtmp[i];
        int r = atomicAdd(&h[u >> 17], 1);   // LDS atomic
        csrsrc[lo + r] = (int)(u & 0x1FFFFu);
    }
}

// ------- gather (bf16 feat rows, 64 B/row): agg[g] = sum over neighbors -------
__global__ __launch_bounds__(256) void gather_kernel(
    const int* __restrict__ start, const int* __restrict__ deg,
    const int* __restrict__ csrsrc, const unsigned short* __restrict__ feat,
    float* __restrict__ agg)
{
    int tid = blockIdx.x * 256 + threadIdx.x;
    int g = tid >> 3;            // node
    int c = tid & 7;             // uint2 chunk (4 bf16) of the 32-dim row
    if (g >= NN) return;
    int s = start[g];
    int e = s + deg[g];
    const uint2* f2 = reinterpret_cast<const uint2*>(feat);
    float4 a0 = make_float4(0.f, 0.f, 0.f, 0.f);
    float4 a1 = make_float4(0.f, 0.f, 0.f, 0.f);
    int i = s;
    for (; i + 2 <= e; i += 2) {
        int s0 = csrsrc[i];
        int s1 = csrsrc[i + 1];
        uint2 v0 = f2[(size_t)s0 * 8 + c];
        uint2 v1 = f2[(size_t)s1 * 8 + c];
        a0.x += bflo(v0.x); a0.y += bfhi(v0.x); a0.z += bflo(v0.y); a0.w += bfhi(v0.y);
        a1.x += bflo(v1.x); a1.y += bfhi(v1.x); a1.z += bflo(v1.y); a1.w += bfhi(v1.y);
    }
    if (i < e) {
        int s0 = csrsrc[i];
        uint2 v0 = f2[(size_t)s0 * 8 + c];
        a0.x += bflo(v0.x); a0.y += bfhi(v0.x); a0.z += bflo(v0.y); a0.w += bfhi(v0.y);
    }
    a0.x += a1.x; a0.y += a1.y; a0.z += a1.z; a0.w += a1.w;
    reinterpret_cast<float4*>(agg)[(size_t)g * 8 + c] = a0;
}

// ---- post layer1: o = agg/deg + b1 + xr; h1 = tanh(l2norm(o));
//      hl(bf16) = h1@W2l, hr(f32) = h1@W2r ----
__global__ __launch_bounds__(256) void post1_kernel(
    const float* __restrict__ agg, const int* __restrict__ deg,
    const float* __restrict__ xr, const float* __restrict__ b1,
    const float* __restrict__ W2l, const float* __restrict__ W2r,
    unsigned short* __restrict__ hlbf, float* __restrict__ hr)
{
    int node = blockIdx.x * 256 + threadIdx.x;
    if (node >= NN) return;
    float inv = 1.0f / fmaxf((float)deg[node], 1.0f);
    float o[DH];
    const float4* ag4 = reinterpret_cast<const float4*>(agg + (size_t)node * DH);
    const float4* xr4 = reinterpret_cast<const float4*>(xr  + (size_t)node * DH);
#pragma unroll
    for (int q = 0; q < DH / 4; ++q) {
        float4 a = ag4[q]; float4 r = xr4[q];
        o[q*4+0] = fmaf(a.x, inv, b1[q*4+0] + r.x);
        o[q*4+1] = fmaf(a.y, inv, b1[q*4+1] + r.y);
        o[q*4+2] = fmaf(a.z, inv, b1[q*4+2] + r.z);
        o[q*4+3] = fmaf(a.w, inv, b1[q*4+3] + r.w);
    }
    float ss = 0.f;
#pragma unroll
    for (int j = 0; j < DH; ++j) ss += o[j] * o[j];
    float rn = 1.0f / fmaxf(sqrtf(ss), 1e-12f);
    float h[DH];
#pragma unroll
    for (int j = 0; j < DH; ++j) h[j] = tanhf(o[j] * rn);

    float al[DH], ar[DH];
#pragma unroll
    for (int j = 0; j < DH; ++j) { al[j] = 0.f; ar[j] = 0.f; }
    for (int k = 0; k < DH; ++k) {
        float hk = h[k];
        const float* wl = W2l + k * DH;
        const float* wr = W2r + k * DH;
#pragma unroll
        for (int j = 0; j < DH; ++j) {
            al[j] = fmaf(hk, wl[j], al[j]);
            ar[j] = fmaf(hk, wr[j], ar[j]);
        }
    }
    unsigned pk[16];
#pragma unroll
    for (int q = 0; q < 16; ++q)
        pk[q] = (unsigned)f2bf(al[q*2]) | ((unsigned)f2bf(al[q*2+1]) << 16);
    uint4* hl4 = reinterpret_cast<uint4*>(hlbf + (size_t)node * DH);
    hl4[0] = make_uint4(pk[0],  pk[1],  pk[2],  pk[3]);
    hl4[1] = make_uint4(pk[4],  pk[5],  pk[6],  pk[7]);
    hl4[2] = make_uint4(pk[8],  pk[9],  pk[10], pk[11]);
    hl4[3] = make_uint4(pk[12], pk[13], pk[14], pk[15]);
    float4* hr4 = reinterpret_cast<float4*>(hr + (size_t)node * DH);
#pragma unroll
    for (int q = 0; q < DH / 4; ++q)
        hr4[q] = make_float4(ar[q*4+0], ar[q*4+1], ar[q*4+2], ar[q*4+3]);
}

// ---- post layer2 + classifier ----
__global__ __launch_bounds__(256) void post2_kernel(
    const float* __restrict__ agg, const int* __restrict__ deg,
    const float* __restrict__ hr, const float* __restrict__ b2,
    const float* __restrict__ Wc, const float* __restrict__ bc,
    float* __restrict__ h2out, float* __restrict__ outp)
{
    int node = blockIdx.x * 256 + threadIdx.x;
    if (node >= NN) return;
    float inv = 1.0f / fmaxf((float)deg[node], 1.0f);
    float o[DH];
    const float4* ag4 = reinterpret_cast<const float4*>(agg + (size_t)node * DH);
    const float4* hr4 = reinterpret_cast<const float4*>(hr  + (size_t)node * DH);
#pragma unroll
    for (int q = 0; q < DH / 4; ++q) {
        float4 a = ag4[q]; float4 r = hr4[q];
        o[q*4+0] = fmaf(a.x, inv, b2[q*4+0] + r.x);
        o[q*4+1] = fmaf(a.y, inv, b2[q*4+1] + r.y);
        o[q*4+2] = fmaf(a.z, inv, b2[q*4+2] + r.z);
        o[q*4+3] = fmaf(a.w, inv, b2[q*4+3] + r.w);
    }
    float ss = 0.f;
#pragma unroll
    for (int j = 0; j < DH; ++j) ss += o[j] * o[j];
    float rn = 1.0f / fmaxf(sqrtf(ss), 1e-12f);
    float h[DH];
#pragma unroll
    for (int j = 0; j < DH; ++j) h[j] = tanhf(o[j] * rn);

    float4* h2o = reinterpret_cast<float4*>(h2out + (size_t)node * DH);
#pragma unroll
    for (int q = 0; q < DH / 4; ++q)
        h2o[q] = make_float4(h[q*4+0], h[q*4+1], h[q*4+2], h[q*4+3]);

    float z[DOUT];
#pragma unroll
    for (int t = 0; t < DOUT; ++t) z[t] = bc[t];
    for (int k = 0; k < DH; ++k) {
        float hk = h[k];
        const float* wc = Wc + k * DOUT;
#pragma unroll
        for (int t = 0; t < DOUT; ++t) z[t] = fmaf(hk, wc[t], z[t]);
    }
    float m = -INFINITY;
#pragma unroll
    for (int t = 0; t < DOUT; ++t) m = fmaxf(m, z[t]);
    float s = 0.f;
#pragma unroll
    for (int t = 0; t < DOUT; ++t) s += expf(z[t] - m);
    float lse = m + logf(s);
    float* orow = outp + (size_t)node * DOUT;
#pragma unroll
    for (int t = 0; t < DOUT; ++t) orow[t] = z[t] - lse;
}

extern "C" void kernel_launch(void* const* d_in, const int* in_sizes, int n_in,
                              void* d_out, int out_size, void* d_ws, size_t ws_size,
                              hipStream_t stream) {
    const float* x   = (const float*)d_in[0];
    const int*   ei  = (const int*)d_in[1];
    const float* W1l = (const float*)d_in[2];
    const float* b1  = (const float*)d_in[3];
    const float* W1r = (const float*)d_in[4];
    const float* W2l = (const float*)d_in[5];
    const float* b2  = (const float*)d_in[6];
    const float* W2r = (const float*)d_in[7];
    const float* Wc  = (const float*)d_in[8];
    const float* bc  = (const float*)d_in[9];

    float* outp = (float*)d_out;                          // [NN, 20]
    float* hout = outp + (size_t)NN * DOUT;               // [NN, 32]

    // workspace layout
    unsigned short* xlbf = (unsigned short*)d_ws;         // NN*DH bf16 (6.4 MB)
    float* xr      = (float*)(xlbf + (size_t)NN * DH);    // NN*DH f32 (also hr)
    float* agg     = xr + (size_t)NN * DH;                // NN*DH f32 (aliases csrtmp)
    unsigned* csrtmp = (unsigned*)agg;                    // NE u32
    int* csrsrc    = (int*)(agg + (size_t)NN * DH);       // NE
    int* deg       = csrsrc + NE;                         // NN
    int* start     = deg + NN;                            // NN
    int* counts    = start + NN;                          // NBLK*NB
    int* offs      = counts + NBLK * NB;                  // NB*NBLK
    int* totals    = offs + NB * NBLK;                    // NB
    int* bases     = totals + NB;                         // NB+1

    const int nodeBlocks  = (NN + 255) / 256;
    const int lin1Blocks  = (NN + NPB - 1) / NPB;
    const int groupBlocks = (NN * 8 + 255) / 256;

    lin1_kernel<<<lin1Blocks, 256, 0, stream>>>(x, W1l, W1r, xlbf, xr);

    countA_kernel<<<NBLK, 256, 0, stream>>>(ei, counts);
    scanB1_kernel<<<NB, 256, 0, stream>>>(counts, offs, totals);
    scanB2_kernel<<<1, 64, 0, stream>>>(totals, bases);
    scatterC_kernel<<<NBLK, 256, 0, stream>>>(ei, offs, bases, csrtmp);
    regroupD_kernel<<<NBUSE, 256, 0, stream>>>(csrtmp, bases, csrsrc, deg, start);

    gather_kernel<<<groupBlocks, 256, 0, stream>>>(start, deg, csrsrc, xlbf, agg);
    post1_kernel<<<nodeBlocks, 256, 0, stream>>>(agg, deg, xr, b1, W2l, W2r, xlbf, xr);

    gather_kernel<<<groupBlocks, 256, 0, stream>>>(start, deg, csrsrc, xlbf, agg);
    post2_kernel<<<nodeBlocks, 256, 0, stream>>>(agg, deg, xr, b2, Wc, bc, hout, outp);
}